// Round 1
// baseline (312.352 us; speedup 1.0000x reference)
//
#include <hip/hip_runtime.h>
#include <hip/hip_bf16.h>
#include <cstdint>

#define D_MODEL 512
#define NHEADS 8
#define HDIM 64
#define SEQ 4096
#define BATCH 2
#define NTOK (BATCH*SEQ)

typedef __bf16 bf16;
typedef __bf16 bfv8 __attribute__((ext_vector_type(8)));
typedef __bf16 bfv4 __attribute__((ext_vector_type(4)));
typedef float f32x4 __attribute__((ext_vector_type(4)));

__device__ __forceinline__ void gload_lds16(const void* g, void* l) {
  __builtin_amdgcn_global_load_lds(
      (const __attribute__((address_space(1))) void*)(uintptr_t)g,
      (__attribute__((address_space(3))) void*)(uintptr_t)l,
      16, 0, 0);
}

// ---------------- converters ----------------
__global__ void k_cvt(const float* __restrict__ in, bf16* __restrict__ out, int n) {
  int i = (blockIdx.x * blockDim.x + threadIdx.x) * 4;
  if (i < n) {
    const float4 v = *(const float4*)(in + i);
    bfv4 b;
    b[0] = (bf16)v.x; b[1] = (bf16)v.y; b[2] = (bf16)v.z; b[3] = (bf16)v.w;
    *(bfv4*)(out + i) = b;
  }
}

// wt[n][k] = w[k][n]  (w is [K][N] row-major)
__global__ void k_cvt_t(const float* __restrict__ w, bf16* __restrict__ wt, int K, int N) {
  int idx = blockIdx.x * blockDim.x + threadIdx.x;
  if (idx < K * N) {
    int n = idx / K, k = idx % K;
    wt[idx] = (bf16)w[k * N + n];
  }
}

// ---------------- GEMM C = A * Bt^T (+bias), A:[M][512] bf16, Bt:[N][512] bf16 ----
// EPI==0: C fp32 -> Cf[M][512]
// EPI==1: QKV split-write: col -> (which,h,dd); Q scaled by 1/8; bf16 out
template<int EPI>
__global__ __launch_bounds__(256) void k_gemm_bt(
    const bf16* __restrict__ A, const bf16* __restrict__ Bt,
    const float* __restrict__ bias,
    float* __restrict__ Cf,
    bf16* __restrict__ Qo, bf16* __restrict__ Ko, bf16* __restrict__ Vo)
{
  __shared__ bf16 As[128 * 32];
  __shared__ bf16 Bs[128 * 32];
  const int t = threadIdx.x;
  const int lane = t & 63;
  const int w = t >> 6;
  const int wm = w >> 1, wn = w & 1;
  const int l15 = lane & 15, l4 = lane >> 4;
  const int bm = blockIdx.y, bn = blockIdx.x;

  const int srow = t >> 2;        // 0..63
  const int scol = (t & 3) * 8;   // 0,8,16,24
  const bf16* gA = A + (size_t)(bm * 128 + srow) * D_MODEL + scol;
  const bf16* gB = Bt + (size_t)(bn * 128 + srow) * D_MODEL + scol;
  bf16* lA = &As[srow * 32 + scol];
  bf16* lB = &Bs[srow * 32 + scol];

  f32x4 acc[4][4] = {};

  for (int kt = 0; kt < D_MODEL / 32; ++kt) {
    const int k0 = kt * 32;
    gload_lds16(gA + k0, lA);
    gload_lds16(gA + (size_t)64 * D_MODEL + k0, lA + 64 * 32);
    gload_lds16(gB + k0, lB);
    gload_lds16(gB + (size_t)64 * D_MODEL + k0, lB + 64 * 32);
    __syncthreads();
    bfv8 af[4], bfr[4];
#pragma unroll
    for (int m = 0; m < 4; ++m)
      af[m] = *(const bfv8*)&As[(wm * 64 + m * 16 + l15) * 32 + l4 * 8];
#pragma unroll
    for (int n = 0; n < 4; ++n)
      bfr[n] = *(const bfv8*)&Bs[(wn * 64 + n * 16 + l15) * 32 + l4 * 8];
#pragma unroll
    for (int m = 0; m < 4; ++m)
#pragma unroll
      for (int n = 0; n < 4; ++n)
        acc[m][n] = __builtin_amdgcn_mfma_f32_16x16x32_bf16(af[m], bfr[n], acc[m][n], 0, 0, 0);
    __syncthreads();
  }

#pragma unroll
  for (int m = 0; m < 4; ++m) {
#pragma unroll
    for (int n = 0; n < 4; ++n) {
      const int col = bn * 128 + wn * 64 + n * 16 + l15;
      const float bv = bias[col];
#pragma unroll
      for (int r = 0; r < 4; ++r) {
        const int row = bm * 128 + wm * 64 + m * 16 + l4 * 4 + r;
        const float val = acc[m][n][r] + bv;
        if constexpr (EPI == 0) {
          Cf[(size_t)row * D_MODEL + col] = val;
        } else {
          const int which = col >> 9;   // 0=Q 1=K 2=V
          const int rem = col & 511;
          const int h = rem >> 6, dd = rem & 63;
          const int b = row >> 12, s = row & 4095;
          const size_t oi = (((size_t)(b * NHEADS + h)) * SEQ + s) * HDIM + dd;
          if (which == 0)      Qo[oi] = (bf16)(val * 0.125f);   // fold 1/sqrt(64)
          else if (which == 1) Ko[oi] = (bf16)val;
          else                 Vo[oi] = (bf16)val;
        }
      }
    }
  }
}

// ---------------- causal flash attention ----------------
// grid: (B*H=16, S/64=64), block 256 (4 waves x 16 q-rows)
__global__ __launch_bounds__(256) void k_attn(
    const bf16* __restrict__ Q, const bf16* __restrict__ Kg,
    const bf16* __restrict__ Vg, bf16* __restrict__ O)
{
  __shared__ bf16 Kl[64][72];       // K tile row-major, +8 pad
  __shared__ bf16 Vt[64][72];       // V tile transposed [d][s]
  __shared__ bf16 Pl[4][16][72];    // per-wave P (C-layout -> A-layout bridge)
  const int t = threadIdx.x;
  const int lane = t & 63, w = t >> 6;
  const int l15 = lane & 15, l4 = lane >> 4;
  const int bh = blockIdx.x;
  const int qt = blockIdx.y;
  const size_t base = (size_t)bh * SEQ * HDIM;
  const int q0 = qt * 64;

  bfv8 qf[2];
  {
    const bf16* qp = Q + base + (size_t)(q0 + w * 16 + l15) * HDIM + l4 * 8;
    qf[0] = *(const bfv8*)qp;
    qf[1] = *(const bfv8*)(qp + 32);
  }
  f32x4 oacc[4] = {};
  float mrow[4] = {-1e30f, -1e30f, -1e30f, -1e30f};
  float lrow[4] = {};

  const int srow = t >> 3;        // 0..31
  const int scol = (t & 7) * 8;   // 0..56

  for (int kt = 0; kt <= qt; ++kt) {
    __syncthreads();   // guard LDS reuse vs previous iteration's reads
    const int kv0 = kt * 64;
#pragma unroll
    for (int c = 0; c < 2; ++c) {
      const int row = srow + c * 32;
      const bfv8 kv = *(const bfv8*)(Kg + base + (size_t)(kv0 + row) * HDIM + scol);
      *(bfv8*)&Kl[row][scol] = kv;
      const bfv8 vv = *(const bfv8*)(Vg + base + (size_t)(kv0 + row) * HDIM + scol);
#pragma unroll
      for (int j = 0; j < 8; ++j) Vt[scol + j][row] = vv[j];
    }
    __syncthreads();

    // S = Q K^T (Q pre-scaled)
    f32x4 sacc[4] = {};
#pragma unroll
    for (int nb = 0; nb < 4; ++nb) {
      const bfv8 kf0 = *(const bfv8*)&Kl[nb * 16 + l15][l4 * 8];
      const bfv8 kf1 = *(const bfv8*)&Kl[nb * 16 + l15][32 + l4 * 8];
      sacc[nb] = __builtin_amdgcn_mfma_f32_16x16x32_bf16(qf[0], kf0, sacc[nb], 0, 0, 0);
      sacc[nb] = __builtin_amdgcn_mfma_f32_16x16x32_bf16(qf[1], kf1, sacc[nb], 0, 0, 0);
    }
    if (kt == qt) {  // diagonal tile causal mask
      const int qloc = w * 16 + l4 * 4;
#pragma unroll
      for (int nb = 0; nb < 4; ++nb) {
        const int kloc = nb * 16 + l15;
#pragma unroll
        for (int r = 0; r < 4; ++r)
          if (kloc > qloc + r) sacc[nb][r] = -1e30f;
      }
    }
    // online softmax: row stats across the 16 lanes sharing each row group
    float pm[4];
#pragma unroll
    for (int r = 0; r < 4; ++r)
      pm[r] = fmaxf(fmaxf(sacc[0][r], sacc[1][r]), fmaxf(sacc[2][r], sacc[3][r]));
#pragma unroll
    for (int msk = 1; msk < 16; msk <<= 1)
#pragma unroll
      for (int r = 0; r < 4; ++r)
        pm[r] = fmaxf(pm[r], __shfl_xor(pm[r], msk));
    float alpha[4];
#pragma unroll
    for (int r = 0; r < 4; ++r) {
      const float mn = fmaxf(mrow[r], pm[r]);
      alpha[r] = expf(mrow[r] - mn);
      mrow[r] = mn;
    }
    float psum[4] = {};
#pragma unroll
    for (int nb = 0; nb < 4; ++nb)
#pragma unroll
      for (int r = 0; r < 4; ++r) {
        const float p = expf(sacc[nb][r] - mrow[r]);
        psum[r] += p;
        Pl[w][l4 * 4 + r][nb * 16 + l15] = (bf16)p;
      }
#pragma unroll
    for (int msk = 1; msk < 16; msk <<= 1)
#pragma unroll
      for (int r = 0; r < 4; ++r)
        psum[r] += __shfl_xor(psum[r], msk);
#pragma unroll
    for (int r = 0; r < 4; ++r)
      lrow[r] = lrow[r] * alpha[r] + psum[r];
#pragma unroll
    for (int nb = 0; nb < 4; ++nb)
#pragma unroll
      for (int r = 0; r < 4; ++r)
        oacc[nb][r] *= alpha[r];
    __syncthreads();   // drain P writes before A-layout reads

    // O += P V
#pragma unroll
    for (int kk = 0; kk < 2; ++kk) {
      const bfv8 pf = *(const bfv8*)&Pl[w][l15][kk * 32 + l4 * 8];
#pragma unroll
      for (int nb = 0; nb < 4; ++nb) {
        const bfv8 vf = *(const bfv8*)&Vt[nb * 16 + l15][kk * 32 + l4 * 8];
        oacc[nb] = __builtin_amdgcn_mfma_f32_16x16x32_bf16(pf, vf, oacc[nb], 0, 0, 0);
      }
    }
  }

  const int b = bh >> 3, h = bh & 7;
#pragma unroll
  for (int nb = 0; nb < 4; ++nb)
#pragma unroll
    for (int r = 0; r < 4; ++r) {
      const int qrow = q0 + w * 16 + l4 * 4 + r;
      const float val = oacc[nb][r] / lrow[r];
      O[((size_t)(b * SEQ + qrow)) * D_MODEL + h * HDIM + nb * 16 + l15] = (bf16)val;
    }
}

// ---------------- launch ----------------
extern "C" void kernel_launch(void* const* d_in, const int* in_sizes, int n_in,
                              void* d_out, int out_size, void* d_ws, size_t ws_size,
                              hipStream_t stream) {
  const float* x    = (const float*)d_in[0];
  const float* Wqkv = (const float*)d_in[1];
  const float* bqkv = (const float*)d_in[2];
  const float* Wo   = (const float*)d_in[3];
  const float* bo   = (const float*)d_in[4];
  float* out = (float*)d_out;

  bf16* xb  = (bf16*)d_ws;                          // 8192*512
  bf16* wqt = xb + (size_t)NTOK * D_MODEL;          // 1536*512
  bf16* wot = wqt + (size_t)1536 * 512;             // 512*512
  bf16* Qb  = wot + (size_t)512 * 512;              // 16*4096*64
  bf16* Kb  = Qb + (size_t)16 * SEQ * HDIM;
  bf16* Vb  = Kb + (size_t)16 * SEQ * HDIM;
  bf16* Ob  = Vb + (size_t)16 * SEQ * HDIM;         // 8192*512

  k_cvt<<<(NTOK * D_MODEL / 4 + 255) / 256, 256, 0, stream>>>(x, xb, NTOK * D_MODEL);
  k_cvt_t<<<(512 * 1536 + 255) / 256, 256, 0, stream>>>(Wqkv, wqt, 512, 1536);
  k_cvt_t<<<(512 * 512 + 255) / 256, 256, 0, stream>>>(Wo, wot, 512, 512);

  k_gemm_bt<1><<<dim3(1536 / 128, NTOK / 128), 256, 0, stream>>>(
      xb, wqt, bqkv, nullptr, Qb, Kb, Vb);

  k_attn<<<dim3(BATCH * NHEADS, SEQ / 64), 256, 0, stream>>>(Qb, Kb, Vb, Ob);

  k_gemm_bt<0><<<dim3(512 / 128, NTOK / 128), 256, 0, stream>>>(
      Ob, wot, bo, out, nullptr, nullptr, nullptr);
}

// Round 2
// 164.331 us; speedup vs baseline: 1.9008x; 1.9008x over previous
//
#include <hip/hip_runtime.h>
#include <hip/hip_bf16.h>
#include <cstdint>

#define D_MODEL 512
#define NHEADS 8
#define HDIM 64
#define SEQ 4096
#define BATCH 2
#define NTOK (BATCH*SEQ)

typedef __bf16 bf16;
typedef __bf16 bfv8 __attribute__((ext_vector_type(8)));
typedef __bf16 bfv4 __attribute__((ext_vector_type(4)));
typedef float f32x4 __attribute__((ext_vector_type(4)));

__device__ __forceinline__ void gload_lds16(const void* g, void* l) {
  __builtin_amdgcn_global_load_lds(
      (const __attribute__((address_space(1))) void*)(uintptr_t)g,
      (__attribute__((address_space(3))) void*)(uintptr_t)l,
      16, 0, 0);
}
__device__ __forceinline__ float exp2_hw(float x) {
  float r; asm("v_exp_f32 %0, %1" : "=v"(r) : "v"(x)); return r;
}
__device__ __forceinline__ unsigned cvtpk_bf16(float lo, float hi) {
  unsigned r; asm("v_cvt_pk_bf16_f32 %0, %1, %2" : "=v"(r) : "v"(lo), "v"(hi)); return r;
}
__device__ __forceinline__ float bpermf(int addr, float v) {
  return __int_as_float(__builtin_amdgcn_ds_bpermute(addr, __float_as_int(v)));
}

// ---------------- converters ----------------
__global__ void k_cvt(const float* __restrict__ in, bf16* __restrict__ out, int n) {
  int i = (blockIdx.x * blockDim.x + threadIdx.x) * 4;
  if (i < n) {
    const float4 v = *(const float4*)(in + i);
    bfv4 b;
    b[0] = (bf16)v.x; b[1] = (bf16)v.y; b[2] = (bf16)v.z; b[3] = (bf16)v.w;
    *(bfv4*)(out + i) = b;
  }
}

__global__ void k_cvt_t(const float* __restrict__ w, bf16* __restrict__ wt, int K, int N) {
  int idx = blockIdx.x * blockDim.x + threadIdx.x;
  if (idx < K * N) {
    int n = idx / K, k = idx % K;
    wt[idx] = (bf16)w[k * N + n];
  }
}

// ---------------- GEMM C = A * Bt^T (+bias) ----------------
// EPI==0: fp32 out. EPI==1: QKV split; Q scaled by 0.125*log2e; V written TRANSPOSED [bh][d][s].
template<int EPI>
__global__ __launch_bounds__(256) void k_gemm_bt(
    const bf16* __restrict__ A, const bf16* __restrict__ Bt,
    const float* __restrict__ bias,
    float* __restrict__ Cf,
    bf16* __restrict__ Qo, bf16* __restrict__ Ko, bf16* __restrict__ Vo)
{
  __shared__ bf16 As[128 * 32];
  __shared__ bf16 Bs[128 * 32];
  const int t = threadIdx.x;
  const int lane = t & 63;
  const int w = t >> 6;
  const int wm = w >> 1, wn = w & 1;
  const int l15 = lane & 15, l4 = lane >> 4;
  const int bm = blockIdx.y, bn = blockIdx.x;

  const int srow = t >> 2;
  const int scol = (t & 3) * 8;
  const bf16* gA = A + (size_t)(bm * 128 + srow) * D_MODEL + scol;
  const bf16* gB = Bt + (size_t)(bn * 128 + srow) * D_MODEL + scol;
  bf16* lA = &As[srow * 32 + scol];
  bf16* lB = &Bs[srow * 32 + scol];

  f32x4 acc[4][4] = {};

  for (int kt = 0; kt < D_MODEL / 32; ++kt) {
    const int k0 = kt * 32;
    gload_lds16(gA + k0, lA);
    gload_lds16(gA + (size_t)64 * D_MODEL + k0, lA + 64 * 32);
    gload_lds16(gB + k0, lB);
    gload_lds16(gB + (size_t)64 * D_MODEL + k0, lB + 64 * 32);
    __syncthreads();
    bfv8 af[4], bfr[4];
#pragma unroll
    for (int m = 0; m < 4; ++m)
      af[m] = *(const bfv8*)&As[(wm * 64 + m * 16 + l15) * 32 + l4 * 8];
#pragma unroll
    for (int n = 0; n < 4; ++n)
      bfr[n] = *(const bfv8*)&Bs[(wn * 64 + n * 16 + l15) * 32 + l4 * 8];
#pragma unroll
    for (int m = 0; m < 4; ++m)
#pragma unroll
      for (int n = 0; n < 4; ++n)
        acc[m][n] = __builtin_amdgcn_mfma_f32_16x16x32_bf16(af[m], bfr[n], acc[m][n], 0, 0, 0);
    __syncthreads();
  }

#pragma unroll
  for (int m = 0; m < 4; ++m) {
#pragma unroll
    for (int n = 0; n < 4; ++n) {
      const int col = bn * 128 + wn * 64 + n * 16 + l15;
      const float bv = bias[col];
#pragma unroll
      for (int r = 0; r < 4; ++r) {
        const int row = bm * 128 + wm * 64 + m * 16 + l4 * 4 + r;
        const float val = acc[m][n][r] + bv;
        if constexpr (EPI == 0) {
          Cf[(size_t)row * D_MODEL + col] = val;
        } else {
          const int which = col >> 9;
          const int rem = col & 511;
          const int h = rem >> 6, dd = rem & 63;
          const int b = row >> 12, s = row & 4095;
          const int bh = b * NHEADS + h;
          if (which == 0)
            Qo[(((size_t)bh) * SEQ + s) * HDIM + dd] = (bf16)(val * 0.18033688f); // 1/8 * log2(e)
          else if (which == 1)
            Ko[(((size_t)bh) * SEQ + s) * HDIM + dd] = (bf16)val;
          else
            Vo[(((size_t)bh) * HDIM + dd) * SEQ + s] = (bf16)val;  // transposed
        }
      }
    }
  }
}

// ---------------- causal flash attention ----------------
// grid: 512 blocks, bh = bx&15, qt = 31-(bx>>4) (heavy-first). 4 waves x 32 q-rows.
// Swapped QK^T: lane owns q-row = l15; K/Vt tiles staged via global_load_lds with
// source-swizzled chunks (XOR row&7), double-buffered, one barrier per tile.
__global__ __launch_bounds__(256) void k_attn(
    const bf16* __restrict__ Q, const bf16* __restrict__ Kg,
    const bf16* __restrict__ Vt, bf16* __restrict__ O)
{
  __shared__ __align__(16) bf16 Kl[2][4096];
  __shared__ __align__(16) bf16 Vl[2][4096];
  __shared__ __align__(16) bf16 Pl[4][1152];   // per-wave [16 q][72]
  const int t = threadIdx.x;
  const int lane = t & 63, w = t >> 6;
  const int l15 = lane & 15, l4 = lane >> 4;
  const int bx = blockIdx.x;
  const int bh = bx & 15;
  const int qt = 31 - (bx >> 4);
  const size_t kqbase = (size_t)bh * SEQ * HDIM;
  const size_t vbase  = (size_t)bh * HDIM * SEQ;
  const int q0 = qt * 128;

  // staging: 512 chunks of 16B per tensor; thread handles chunks t and t+256.
  // chunk ch -> LDS row=ch>>3, chunk-col=ch&7; global source col = (ch&7)^(row&7).
  const int ch0 = t, ch1 = t + 256;
  const int r0 = ch0 >> 3, c0 = ((ch0 & 7) ^ (r0 & 7)) * 8;
  const int r1 = ch1 >> 3, c1 = ((ch1 & 7) ^ (r1 & 7)) * 8;
  const bf16* kgp0 = Kg + kqbase + (size_t)r0 * HDIM + c0;
  const bf16* kgp1 = Kg + kqbase + (size_t)r1 * HDIM + c1;
  const bf16* vgp0 = Vt + vbase + (size_t)r0 * SEQ + c0;
  const bf16* vgp1 = Vt + vbase + (size_t)r1 * SEQ + c1;

  // Q fragments (B-operand: row=q=l15, k-dim=d)
  bfv8 qf[2][2];
#pragma unroll
  for (int mf = 0; mf < 2; ++mf) {
    const bf16* qp = Q + kqbase + (size_t)(q0 + w * 32 + mf * 16 + l15) * HDIM + l4 * 8;
    qf[mf][0] = *(const bfv8*)qp;
    qf[mf][1] = *(const bfv8*)(qp + 32);
  }
  const int qg[2] = { q0 + w * 32 + l15, q0 + w * 32 + 16 + l15 };
  const int bp[4] = { l4 * 16, l4 * 16 + 4, l4 * 16 + 8, l4 * 16 + 12 };

  f32x4 oacc[2][4] = {};
  float mreg[2] = { -1e30f, -1e30f };
  float lreg[2] = { 0.f, 0.f };

  const int nt = 2 * qt + 2;

  // prologue: stage tile 0 into buf 0
  gload_lds16(kgp0, &Kl[0][ch0 * 8]);
  gload_lds16(kgp1, &Kl[0][ch1 * 8]);
  gload_lds16(vgp0, &Vl[0][ch0 * 8]);
  gload_lds16(vgp1, &Vl[0][ch1 * 8]);
  __syncthreads();

  for (int kt = 0; kt < nt; ++kt) {
    const int buf = kt & 1;
    if (kt + 1 < nt) {
      const int nv0 = (kt + 1) * 64;
      gload_lds16(kgp0 + (size_t)nv0 * HDIM, &Kl[buf ^ 1][ch0 * 8]);
      gload_lds16(kgp1 + (size_t)nv0 * HDIM, &Kl[buf ^ 1][ch1 * 8]);
      gload_lds16(vgp0 + nv0, &Vl[buf ^ 1][ch0 * 8]);
      gload_lds16(vgp1 + nv0, &Vl[buf ^ 1][ch1 * 8]);
    }
    const int kv0 = kt * 64;

    // QK^T swapped: st[mf][nb][r] = S[q=l15][k=kv0+nb*16+l4*4+r]
    f32x4 st[2][4] = {};
#pragma unroll
    for (int nb = 0; nb < 4; ++nb)
#pragma unroll
      for (int kk = 0; kk < 2; ++kk) {
        const bfv8 kf = *(const bfv8*)&Kl[buf][(nb * 16 + l15) * HDIM +
                                              (((kk * 4 + l4) ^ (l15 & 7)) * 8)];
        st[0][nb] = __builtin_amdgcn_mfma_f32_16x16x32_bf16(kf, qf[0][kk], st[0][nb], 0, 0, 0);
        st[1][nb] = __builtin_amdgcn_mfma_f32_16x16x32_bf16(kf, qf[1][kk], st[1][nb], 0, 0, 0);
      }

    if (kt >= 2 * qt) {   // diagonal tiles: causal mask
#pragma unroll
      for (int nb = 0; nb < 4; ++nb)
#pragma unroll
        for (int r = 0; r < 4; ++r) {
          const int kgi = kv0 + nb * 16 + l4 * 4 + r;
          if (kgi > qg[0]) st[0][nb][r] = -1e30f;
          if (kgi > qg[1]) st[1][nb][r] = -1e30f;
        }
    }

    // V fragments (B-operand: row=d=l15, k-dim=kv)
    bfv8 vf[4][2];
#pragma unroll
    for (int nd = 0; nd < 4; ++nd)
#pragma unroll
      for (int kk = 0; kk < 2; ++kk)
        vf[nd][kk] = *(const bfv8*)&Vl[buf][(nd * 16 + l15) * HDIM +
                                            (((kk * 4 + l4) ^ (l15 & 7)) * 8)];

#pragma unroll
    for (int mf = 0; mf < 2; ++mf) {
      float pm = st[mf][0][0];
#pragma unroll
      for (int nb = 0; nb < 4; ++nb)
#pragma unroll
        for (int r = 0; r < 4; ++r) pm = fmaxf(pm, st[mf][nb][r]);
      pm = fmaxf(pm, __shfl_xor(pm, 16));
      pm = fmaxf(pm, __shfl_xor(pm, 32));
      const float mn = fmaxf(mreg[mf], pm);
      const float al = exp2_hw(mreg[mf] - mn);
      mreg[mf] = mn;
      float ps = 0.f;
#pragma unroll
      for (int nb = 0; nb < 4; ++nb)
#pragma unroll
        for (int r = 0; r < 4; ++r) {
          const float p = exp2_hw(st[mf][nb][r] - mn);
          st[mf][nb][r] = p;
          ps += p;
        }
      ps += __shfl_xor(ps, 16);
      ps += __shfl_xor(ps, 32);
      lreg[mf] = lreg[mf] * al + ps;

      float alr[4];
#pragma unroll
      for (int r = 0; r < 4; ++r) alr[r] = bpermf(bp[r], al);
#pragma unroll
      for (int nd = 0; nd < 4; ++nd)
#pragma unroll
        for (int r = 0; r < 4; ++r) oacc[mf][nd][r] *= alr[r];

      // pack P (bf16 pairs along k) -> per-wave LDS, vectorized b64
      asm volatile("" ::: "memory");
#pragma unroll
      for (int nb = 0; nb < 4; ++nb) {
        uint2 u;
        u.x = cvtpk_bf16(st[mf][nb][0], st[mf][nb][1]);
        u.y = cvtpk_bf16(st[mf][nb][2], st[mf][nb][3]);
        *(uint2*)&Pl[w][l15 * 72 + nb * 16 + l4 * 4] = u;
      }
      asm volatile("" ::: "memory");

      // O += P V
#pragma unroll
      for (int kk = 0; kk < 2; ++kk) {
        const bfv8 pf = *(const bfv8*)&Pl[w][l15 * 72 + kk * 32 + l4 * 8];
#pragma unroll
        for (int nd = 0; nd < 4; ++nd)
          oacc[mf][nd] = __builtin_amdgcn_mfma_f32_16x16x32_bf16(pf, vf[nd][kk], oacc[mf][nd], 0, 0, 0);
      }
    }
    __syncthreads();
  }

  const int b = bh >> 3, h = bh & 7;
#pragma unroll
  for (int mf = 0; mf < 2; ++mf) {
    const float linv = 1.0f / lreg[mf];
    float lr[4];
#pragma unroll
    for (int r = 0; r < 4; ++r) lr[r] = bpermf(bp[r], linv);
#pragma unroll
    for (int nd = 0; nd < 4; ++nd)
#pragma unroll
      for (int r = 0; r < 4; ++r) {
        const int q = q0 + w * 32 + mf * 16 + l4 * 4 + r;
        O[((size_t)(b * SEQ + q)) * D_MODEL + h * HDIM + nd * 16 + l15] =
            (bf16)(oacc[mf][nd][r] * lr[r]);
      }
  }
}

// ---------------- launch ----------------
extern "C" void kernel_launch(void* const* d_in, const int* in_sizes, int n_in,
                              void* d_out, int out_size, void* d_ws, size_t ws_size,
                              hipStream_t stream) {
  const float* x    = (const float*)d_in[0];
  const float* Wqkv = (const float*)d_in[1];
  const float* bqkv = (const float*)d_in[2];
  const float* Wo   = (const float*)d_in[3];
  const float* bo   = (const float*)d_in[4];
  float* out = (float*)d_out;

  bf16* xb  = (bf16*)d_ws;
  bf16* wqt = xb + (size_t)NTOK * D_MODEL;
  bf16* wot = wqt + (size_t)1536 * 512;
  bf16* Qb  = wot + (size_t)512 * 512;
  bf16* Kb  = Qb + (size_t)16 * SEQ * HDIM;
  bf16* Vb  = Kb + (size_t)16 * SEQ * HDIM;   // holds V TRANSPOSED [bh][d][s]
  bf16* Ob  = Vb + (size_t)16 * SEQ * HDIM;

  k_cvt<<<(NTOK * D_MODEL / 4 + 255) / 256, 256, 0, stream>>>(x, xb, NTOK * D_MODEL);
  k_cvt_t<<<(512 * 1536 + 255) / 256, 256, 0, stream>>>(Wqkv, wqt, 512, 1536);
  k_cvt_t<<<(512 * 512 + 255) / 256, 256, 0, stream>>>(Wo, wot, 512, 512);

  k_gemm_bt<1><<<dim3(1536 / 128, NTOK / 128), 256, 0, stream>>>(
      xb, wqt, bqkv, nullptr, Qb, Kb, Vb);

  k_attn<<<dim3(512), 256, 0, stream>>>(Qb, Kb, Vb, Ob);

  k_gemm_bt<0><<<dim3(512 / 128, NTOK / 128), 256, 0, stream>>>(
      Ob, wot, bo, out, nullptr, nullptr, nullptr);
}

// Round 3
// 131.847 us; speedup vs baseline: 2.3691x; 1.2464x over previous
//
#include <hip/hip_runtime.h>
#include <hip/hip_bf16.h>
#include <cstdint>

#define D_MODEL 512
#define NHEADS 8
#define HDIM 64
#define SEQ 4096
#define BATCH 2
#define NTOK (BATCH*SEQ)

typedef __bf16 bf16;
typedef __bf16 bfv8 __attribute__((ext_vector_type(8)));
typedef __bf16 bfv4 __attribute__((ext_vector_type(4)));
typedef float f32x4 __attribute__((ext_vector_type(4)));
typedef unsigned u32x2 __attribute__((ext_vector_type(2)));

__device__ __forceinline__ void gload_lds16(const void* g, void* l) {
  __builtin_amdgcn_global_load_lds(
      (const __attribute__((address_space(1))) void*)(uintptr_t)g,
      (__attribute__((address_space(3))) void*)(uintptr_t)l,
      16, 0, 0);
}
__device__ __forceinline__ float exp2_hw(float x) {
  float r; asm("v_exp_f32 %0, %1" : "=v"(r) : "v"(x)); return r;
}
__device__ __forceinline__ unsigned cvtpk_bf16(float lo, float hi) {
  unsigned r; asm("v_cvt_pk_bf16_f32 %0, %1, %2" : "=v"(r) : "v"(lo), "v"(hi)); return r;
}
__device__ __forceinline__ float bpermf(int addr, float v) {
  return __int_as_float(__builtin_amdgcn_ds_bpermute(addr, __float_as_int(v)));
}
// cross-lane pair {x[lane], x[lane^32]} via permlane32_swap (VALU pipe, not LDS)
__device__ __forceinline__ void swap32(float x, float& a, float& b) {
  u32x2 r = __builtin_amdgcn_permlane32_swap(__float_as_uint(x), __float_as_uint(x), false, false);
  a = __uint_as_float(r[0]); b = __uint_as_float(r[1]);
}

// ---------------- converters ----------------
__global__ void k_cvt(const float* __restrict__ in, bf16* __restrict__ out, int n) {
  int i = (blockIdx.x * blockDim.x + threadIdx.x) * 4;
  if (i < n) {
    const float4 v = *(const float4*)(in + i);
    bfv4 b;
    b[0] = (bf16)v.x; b[1] = (bf16)v.y; b[2] = (bf16)v.z; b[3] = (bf16)v.w;
    *(bfv4*)(out + i) = b;
  }
}

// tiled transpose+cast: w [K][N] f32 -> wt [N][K] bf16 (coalesced both sides)
__global__ __launch_bounds__(256) void k_cvt_t(
    const float* __restrict__ w, bf16* __restrict__ wt, int K, int N) {
  __shared__ float tile[64][65];
  const int n0 = blockIdx.x * 64, k0 = blockIdx.y * 64;
  const int c = threadIdx.x & 63, r0 = threadIdx.x >> 6;
#pragma unroll
  for (int i = 0; i < 16; ++i) {
    const int r = r0 + i * 4;
    tile[r][c] = w[(size_t)(k0 + r) * N + n0 + c];
  }
  __syncthreads();
#pragma unroll
  for (int i = 0; i < 16; ++i) {
    const int r = r0 + i * 4;
    wt[(size_t)(n0 + r) * K + k0 + c] = (bf16)tile[c][r];
  }
}

// ---------------- GEMM C = A * Bt^T (+bias) ----------------
template<int EPI>
__global__ __launch_bounds__(256) void k_gemm_bt(
    const bf16* __restrict__ A, const bf16* __restrict__ Bt,
    const float* __restrict__ bias,
    float* __restrict__ Cf,
    bf16* __restrict__ Qo, bf16* __restrict__ Ko, bf16* __restrict__ Vo)
{
  __shared__ bf16 As[128 * 32];
  __shared__ bf16 Bs[128 * 32];
  const int t = threadIdx.x;
  const int lane = t & 63;
  const int w = t >> 6;
  const int wm = w >> 1, wn = w & 1;
  const int l15 = lane & 15, l4 = lane >> 4;
  const int bm = blockIdx.y, bn = blockIdx.x;

  const int srow = t >> 2;
  const int scol = (t & 3) * 8;
  const bf16* gA = A + (size_t)(bm * 128 + srow) * D_MODEL + scol;
  const bf16* gB = Bt + (size_t)(bn * 128 + srow) * D_MODEL + scol;
  bf16* lA = &As[srow * 32 + scol];
  bf16* lB = &Bs[srow * 32 + scol];

  f32x4 acc[4][4] = {};

  for (int kt = 0; kt < D_MODEL / 32; ++kt) {
    const int k0 = kt * 32;
    gload_lds16(gA + k0, lA);
    gload_lds16(gA + (size_t)64 * D_MODEL + k0, lA + 64 * 32);
    gload_lds16(gB + k0, lB);
    gload_lds16(gB + (size_t)64 * D_MODEL + k0, lB + 64 * 32);
    __syncthreads();
    bfv8 af[4], bfr[4];
#pragma unroll
    for (int m = 0; m < 4; ++m)
      af[m] = *(const bfv8*)&As[(wm * 64 + m * 16 + l15) * 32 + l4 * 8];
#pragma unroll
    for (int n = 0; n < 4; ++n)
      bfr[n] = *(const bfv8*)&Bs[(wn * 64 + n * 16 + l15) * 32 + l4 * 8];
#pragma unroll
    for (int m = 0; m < 4; ++m)
#pragma unroll
      for (int n = 0; n < 4; ++n)
        acc[m][n] = __builtin_amdgcn_mfma_f32_16x16x32_bf16(af[m], bfr[n], acc[m][n], 0, 0, 0);
    __syncthreads();
  }

#pragma unroll
  for (int m = 0; m < 4; ++m) {
#pragma unroll
    for (int n = 0; n < 4; ++n) {
      const int col = bn * 128 + wn * 64 + n * 16 + l15;
      const float bv = bias[col];
#pragma unroll
      for (int r = 0; r < 4; ++r) {
        const int row = bm * 128 + wm * 64 + m * 16 + l4 * 4 + r;
        const float val = acc[m][n][r] + bv;
        if constexpr (EPI == 0) {
          Cf[(size_t)row * D_MODEL + col] = val;
        } else {
          const int which = col >> 9;
          const int rem = col & 511;
          const int h = rem >> 6, dd = rem & 63;
          const int b = row >> 12, s = row & 4095;
          const int bh = b * NHEADS + h;
          if (which == 0)
            Qo[(((size_t)bh) * SEQ + s) * HDIM + dd] = (bf16)(val * 0.18033688f); // 1/8*log2(e)
          else if (which == 1)
            Ko[(((size_t)bh) * SEQ + s) * HDIM + dd] = (bf16)val;
          else
            Vo[(((size_t)bh) * HDIM + dd) * SEQ + s] = (bf16)val;  // transposed
        }
      }
    }
  }
}

// ---------------- causal flash attention ----------------
// 512 blocks heavy-first; 8 waves x 16 q-rows (QBLK=128). Swapped QK^T, lane owns q-row.
// K/V double-buffered via source-swizzled global_load_lds; defer-rescale softmax.
__global__ __launch_bounds__(512, 4) void k_attn(
    const bf16* __restrict__ Q, const bf16* __restrict__ Kg,
    const bf16* __restrict__ Vt, bf16* __restrict__ O)
{
  __shared__ __align__(16) bf16 Kl[2][4096];
  __shared__ __align__(16) bf16 Vl[2][4096];
  __shared__ __align__(16) bf16 Pl[8][1152];   // per-wave [16 q][72]
  const int t = threadIdx.x;
  const int lane = t & 63, w = t >> 6;
  const int l15 = lane & 15, l4 = lane >> 4;
  const int bx = blockIdx.x;
  const int bh = bx & 15;
  const int qt = 31 - (bx >> 4);
  const size_t kqbase = (size_t)bh * SEQ * HDIM;
  const size_t vbase  = (size_t)bh * HDIM * SEQ;
  const int q0 = qt * 128;

  // staging: 512 chunks of 16B per tensor; thread t handles chunk t.
  const int r0 = t >> 3, c0 = ((t & 7) ^ (r0 & 7)) * 8;
  const bf16* kgp = Kg + kqbase + (size_t)r0 * HDIM + c0;
  const bf16* vgp = Vt + vbase + (size_t)r0 * SEQ + c0;

  bfv8 qf[2];
  {
    const bf16* qp = Q + kqbase + (size_t)(q0 + w * 16 + l15) * HDIM + l4 * 8;
    qf[0] = *(const bfv8*)qp;
    qf[1] = *(const bfv8*)(qp + 32);
  }
  const int qg = q0 + w * 16 + l15;
  const int wqmax = q0 + w * 16 + 15;
  const int bp[4] = { l4 * 16, l4 * 16 + 4, l4 * 16 + 8, l4 * 16 + 12 };

  f32x4 oacc[4] = {};
  float mreg = -1e30f;
  float lreg = 0.f;

  const int nt = 2 * qt + 2;

  gload_lds16(kgp, &Kl[0][t * 8]);
  gload_lds16(vgp, &Vl[0][t * 8]);
  __syncthreads();

  for (int kt = 0; kt < nt; ++kt) {
    const int buf = kt & 1;
    if (kt + 1 < nt) {
      const int nv0 = (kt + 1) * 64;
      gload_lds16(kgp + (size_t)nv0 * HDIM, &Kl[buf ^ 1][t * 8]);
      gload_lds16(vgp + nv0, &Vl[buf ^ 1][t * 8]);
    }
    const int kv0 = kt * 64;

    if (kv0 <= wqmax) {   // wave has at least one unmasked column
      // QK^T swapped: st[nb][r] = S[q=l15][k=kv0+nb*16+l4*4+r]
      f32x4 st[4] = {};
      __builtin_amdgcn_s_setprio(1);
#pragma unroll
      for (int nb = 0; nb < 4; ++nb)
#pragma unroll
        for (int kk = 0; kk < 2; ++kk) {
          const bfv8 kf = *(const bfv8*)&Kl[buf][(nb * 16 + l15) * HDIM +
                                                (((kk * 4 + l4) ^ (l15 & 7)) * 8)];
          st[nb] = __builtin_amdgcn_mfma_f32_16x16x32_bf16(kf, qf[kk], st[nb], 0, 0, 0);
        }
      __builtin_amdgcn_s_setprio(0);

      if (kt >= 2 * qt) {   // diagonal tiles: causal mask
#pragma unroll
        for (int nb = 0; nb < 4; ++nb)
#pragma unroll
          for (int r = 0; r < 4; ++r) {
            const int kgi = kv0 + nb * 16 + l4 * 4 + r;
            if (kgi > qg) st[nb][r] = -1e30f;
          }
      }

      // V fragments (hide ds latency under softmax VALU)
      bfv8 vf[4][2];
#pragma unroll
      for (int nd = 0; nd < 4; ++nd)
#pragma unroll
        for (int kk = 0; kk < 2; ++kk)
          vf[nd][kk] = *(const bfv8*)&Vl[buf][(nd * 16 + l15) * HDIM +
                                              (((kk * 4 + l4) ^ (l15 & 7)) * 8)];

      // row max (in-lane tree + xor16 + permlane32)
      float pmn[4];
#pragma unroll
      for (int nb = 0; nb < 4; ++nb)
        pmn[nb] = fmaxf(fmaxf(st[nb][0], st[nb][1]), fmaxf(st[nb][2], st[nb][3]));
      float pm = fmaxf(fmaxf(pmn[0], pmn[1]), fmaxf(pmn[2], pmn[3]));
      pm = fmaxf(pm, __shfl_xor(pm, 16));
      { float a, b; swap32(pm, a, b); pm = fmaxf(a, b); }

      // defer-rescale (T13): wave-uniform
      if (!__all(pm - mreg <= 8.0f)) {
        const float mn = fmaxf(mreg, pm);
        const float al = exp2_hw(mreg - mn);
        mreg = mn;
        float alr[4];
#pragma unroll
        for (int r = 0; r < 4; ++r) alr[r] = bpermf(bp[r], al);
#pragma unroll
        for (int nd = 0; nd < 4; ++nd)
#pragma unroll
          for (int r = 0; r < 4; ++r) oacc[nd][r] *= alr[r];
        lreg *= al;
      }

      // P = exp2(st - m), row sum
      float ps[4] = {};
#pragma unroll
      for (int nb = 0; nb < 4; ++nb)
#pragma unroll
        for (int r = 0; r < 4; ++r) {
          const float p = exp2_hw(st[nb][r] - mreg);
          st[nb][r] = p;
          ps[nb] += p;
        }
      float pss = (ps[0] + ps[1]) + (ps[2] + ps[3]);
      pss += __shfl_xor(pss, 16);
      { float a, b; swap32(pss, a, b); pss = a + b; }
      lreg += pss;

      // pack P -> per-wave LDS (C-layout -> A-layout bridge)
      asm volatile("" ::: "memory");
#pragma unroll
      for (int nb = 0; nb < 4; ++nb) {
        uint2 u;
        u.x = cvtpk_bf16(st[nb][0], st[nb][1]);
        u.y = cvtpk_bf16(st[nb][2], st[nb][3]);
        *(uint2*)&Pl[w][l15 * 72 + nb * 16 + l4 * 4] = u;
      }
      asm volatile("" ::: "memory");

      // O += P V
      __builtin_amdgcn_s_setprio(1);
#pragma unroll
      for (int kk = 0; kk < 2; ++kk) {
        const bfv8 pf = *(const bfv8*)&Pl[w][l15 * 72 + kk * 32 + l4 * 8];
#pragma unroll
        for (int nd = 0; nd < 4; ++nd)
          oacc[nd] = __builtin_amdgcn_mfma_f32_16x16x32_bf16(pf, vf[nd][kk], oacc[nd], 0, 0, 0);
      }
      __builtin_amdgcn_s_setprio(0);
    }
    __syncthreads();
  }

  const int b = bh >> 3, h = bh & 7;
  const float linv = 1.0f / lreg;
  float lr[4];
#pragma unroll
  for (int r = 0; r < 4; ++r) lr[r] = bpermf(bp[r], linv);
#pragma unroll
  for (int nd = 0; nd < 4; ++nd)
#pragma unroll
    for (int r = 0; r < 4; ++r) {
      const int q = q0 + w * 16 + l4 * 4 + r;
      O[((size_t)(b * SEQ + q)) * D_MODEL + h * HDIM + nd * 16 + l15] =
          (bf16)(oacc[nd][r] * lr[r]);
    }
}

// ---------------- launch ----------------
extern "C" void kernel_launch(void* const* d_in, const int* in_sizes, int n_in,
                              void* d_out, int out_size, void* d_ws, size_t ws_size,
                              hipStream_t stream) {
  const float* x    = (const float*)d_in[0];
  const float* Wqkv = (const float*)d_in[1];
  const float* bqkv = (const float*)d_in[2];
  const float* Wo   = (const float*)d_in[3];
  const float* bo   = (const float*)d_in[4];
  float* out = (float*)d_out;

  bf16* xb  = (bf16*)d_ws;
  bf16* wqt = xb + (size_t)NTOK * D_MODEL;
  bf16* wot = wqt + (size_t)1536 * 512;
  bf16* Qb  = wot + (size_t)512 * 512;
  bf16* Kb  = Qb + (size_t)16 * SEQ * HDIM;
  bf16* Vb  = Kb + (size_t)16 * SEQ * HDIM;   // V transposed [bh][d][s]
  bf16* Ob  = Vb + (size_t)16 * SEQ * HDIM;

  k_cvt<<<(NTOK * D_MODEL / 4 + 255) / 256, 256, 0, stream>>>(x, xb, NTOK * D_MODEL);
  k_cvt_t<<<dim3(1536 / 64, 512 / 64), 256, 0, stream>>>(Wqkv, wqt, 512, 1536);
  k_cvt_t<<<dim3(512 / 64, 512 / 64), 256, 0, stream>>>(Wo, wot, 512, 512);

  k_gemm_bt<1><<<dim3(1536 / 128, NTOK / 128), 256, 0, stream>>>(
      xb, wqt, bqkv, nullptr, Qb, Kb, Vb);

  k_attn<<<dim3(512), 512, 0, stream>>>(Qb, Kb, Vb, Ob);

  k_gemm_bt<0><<<dim3(512 / 128, NTOK / 128), 256, 0, stream>>>(
      Ob, wot, bo, out, nullptr, nullptr, nullptr);
}